// Round 1
// baseline (1037.613 us; speedup 1.0000x reference)
//
#include <hip/hip_runtime.h>
#include <math.h>

#define N_NODES 50000
#define N_EDGES 1600000
#define DIM 128
#define EPS 1e-5f
#define SLOPE 0.2f

__device__ __forceinline__ float lrelu(float x) { return x > 0.f ? x : SLOPE * x; }

// ---------------- CSR build ----------------
__global__ void k_degree(const int* __restrict__ dst, int* __restrict__ deg) {
    int e = blockIdx.x * blockDim.x + threadIdx.x;
    if (e < N_EDGES) atomicAdd(&deg[dst[e]], 1);
}

__global__ void k_scan(const int* __restrict__ deg, int* __restrict__ row_ptr) {
    __shared__ int sdata[1024];
    __shared__ int s_running;
    int t = threadIdx.x;
    if (t == 0) s_running = 0;
    __syncthreads();
    for (int base = 0; base < N_NODES; base += 1024) {
        int v = (base + t < N_NODES) ? deg[base + t] : 0;
        sdata[t] = v;
        __syncthreads();
        for (int off = 1; off < 1024; off <<= 1) {
            int x = sdata[t];
            int y = (t >= off) ? sdata[t - off] : 0;
            __syncthreads();
            sdata[t] = x + y;
            __syncthreads();
        }
        int incl = sdata[t];
        int run = s_running;
        __syncthreads();                 // everyone read s_running before update
        if (t == 1023) s_running = run + incl;
        if (base + t < N_NODES) row_ptr[base + t] = run + incl - v;  // exclusive
        __syncthreads();
    }
    if (t == 0) row_ptr[N_NODES] = s_running;
}

__global__ void k_scatter(const int* __restrict__ src, const int* __restrict__ dst,
                          const int* __restrict__ row_ptr, int* __restrict__ fill,
                          int* __restrict__ col_src) {
    int e = blockIdx.x * blockDim.x + threadIdx.x;
    if (e < N_EDGES) {
        int d = dst[e];
        int pos = row_ptr[d] + atomicAdd(&fill[d], 1);
        col_src[pos] = src[e];
    }
}

// ---------------- GEMM: H = Z @ W  (fp32, 32 rows x 128 cols per 256-thread block, 4x4/thread)
__global__ void k_gemm(const float* __restrict__ Z, const float* __restrict__ W,
                       float* __restrict__ H) {
    __shared__ float zT[128][36];   // [k][r], stride 144B (16B aligned)
    __shared__ float Ws[64][128];   // half-K chunk of W
    int tid = threadIdx.x;
    int row0 = blockIdx.x * 32;

    for (int i = tid; i < 32 * 128; i += 256) {
        int r = i >> 7;
        int k = i & 127;
        int gr = row0 + r;
        zT[k][r] = (gr < N_NODES) ? Z[gr * 128 + k] : 0.f;
    }

    float acc[4][4];
#pragma unroll
    for (int a = 0; a < 4; a++)
#pragma unroll
        for (int b = 0; b < 4; b++) acc[a][b] = 0.f;

    int cg = tid & 31;   // col group: cols cg*4 .. cg*4+3
    int rg = tid >> 5;   // row group: rows rg*4 .. rg*4+3

    for (int kc = 0; kc < 2; ++kc) {
        __syncthreads();
        for (int i = tid; i < 64 * 128 / 4; i += 256) {
            int k = i >> 5;
            int c4 = i & 31;
            *(float4*)&Ws[k][c4 * 4] = *(const float4*)&W[(kc * 64 + k) * 128 + c4 * 4];
        }
        __syncthreads();
#pragma unroll 8
        for (int kk = 0; kk < 64; ++kk) {
            int k = kc * 64 + kk;
            float4 wv = *(float4*)&Ws[kk][cg * 4];
            float4 zv = *(float4*)&zT[k][rg * 4];
            acc[0][0] += zv.x * wv.x; acc[0][1] += zv.x * wv.y; acc[0][2] += zv.x * wv.z; acc[0][3] += zv.x * wv.w;
            acc[1][0] += zv.y * wv.x; acc[1][1] += zv.y * wv.y; acc[1][2] += zv.y * wv.z; acc[1][3] += zv.y * wv.w;
            acc[2][0] += zv.z * wv.x; acc[2][1] += zv.z * wv.y; acc[2][2] += zv.z * wv.z; acc[2][3] += zv.z * wv.w;
            acc[3][0] += zv.w * wv.x; acc[3][1] += zv.w * wv.y; acc[3][2] += zv.w * wv.z; acc[3][3] += zv.w * wv.w;
        }
    }

#pragma unroll
    for (int a = 0; a < 4; a++) {
        int gr = row0 + rg * 4 + a;
        if (gr < N_NODES)
            *(float4*)&H[gr * 128 + cg * 4] =
                make_float4(acc[a][0], acc[a][1], acc[a][2], acc[a][3]);
    }
}

// ---------------- per-node attention coefficients: as = h.a_src, ad = h.a_dst
__global__ void k_alpha(const float* __restrict__ H, const float* __restrict__ a_src,
                        const float* __restrict__ a_dst, float* __restrict__ as_,
                        float* __restrict__ ad_) {
    int node = blockIdx.x * 4 + (threadIdx.x >> 6);
    int lane = threadIdx.x & 63;
    if (node >= N_NODES) return;
    float2 h = *(const float2*)&H[node * 128 + lane * 2];
    float2 s = *(const float2*)&a_src[lane * 2];
    float2 d = *(const float2*)&a_dst[lane * 2];
    float ps = h.x * s.x + h.y * s.y;
    float pd = h.x * d.x + h.y * d.y;
#pragma unroll
    for (int off = 32; off; off >>= 1) {
        ps += __shfl_xor(ps, off);
        pd += __shfl_xor(pd, off);
    }
    if (lane == 0) { as_[node] = ps; ad_[node] = pd; }
}

// ---------------- segment softmax + weighted aggregation (one wave per dst node)
__global__ void k_aggregate(const int* __restrict__ row_ptr, const int* __restrict__ col_src,
                            const float* __restrict__ H, const float* __restrict__ as_,
                            const float* __restrict__ ad_, const float* __restrict__ bias,
                            float* __restrict__ Zout, float* __restrict__ ebuf) {
    int node = blockIdx.x * 4 + (threadIdx.x >> 6);
    int lane = threadIdx.x & 63;
    if (node >= N_NODES) return;

    int start = row_ptr[node], end = row_ptr[node + 1];
    int deg = end - start;
    float ad_i = ad_[node];
    float eself = lrelu(as_[node] + ad_i);
    float m = eself;
    float2 acc;
    float2 hi = *(const float2*)&H[node * 128 + lane * 2];

    if (deg <= 128) {
        int s0 = 0, s1 = 0;
        float e0 = -INFINITY, e1 = -INFINITY;
        if (start + lane < end) {
            s0 = col_src[start + lane];
            e0 = lrelu(as_[s0] + ad_i);
            m = fmaxf(m, e0);
        }
        if (start + 64 + lane < end) {
            s1 = col_src[start + 64 + lane];
            e1 = lrelu(as_[s1] + ad_i);
            m = fmaxf(m, e1);
        }
#pragma unroll
        for (int off = 32; off; off >>= 1) m = fmaxf(m, __shfl_xor(m, off));
        float p = __expf(e0 - m) + __expf(e1 - m);   // exp(-inf)=0 for invalid
#pragma unroll
        for (int off = 32; off; off >>= 1) p += __shfl_xor(p, off);
        float pself = __expf(eself - m);
        float inv_s = 1.f / (p + pself);
        float wself = pself * inv_s;
        acc.x = wself * hi.x;
        acc.y = wself * hi.y;
        for (int j = 0; j < deg; ++j) {
            int hold = j & 63;
            float ev = (j < 64) ? __shfl(e0, hold) : __shfl(e1, hold);
            int sv = (j < 64) ? __shfl(s0, hold) : __shfl(s1, hold);
            float w = __expf(ev - m) * inv_s;
            float2 hs = *(const float2*)&H[sv * 128 + lane * 2];
            acc.x += w * hs.x;
            acc.y += w * hs.y;
        }
    } else {
        for (int j = start + lane; j < end; j += 64) {
            int sj = col_src[j];
            float e = lrelu(as_[sj] + ad_i);
            ebuf[j] = e;
            m = fmaxf(m, e);
        }
#pragma unroll
        for (int off = 32; off; off >>= 1) m = fmaxf(m, __shfl_xor(m, off));
        float p = 0.f;
        for (int j = start + lane; j < end; j += 64) p += __expf(ebuf[j] - m);
#pragma unroll
        for (int off = 32; off; off >>= 1) p += __shfl_xor(p, off);
        float pself = __expf(eself - m);
        float inv_s = 1.f / (p + pself);
        float wself = pself * inv_s;
        acc.x = wself * hi.x;
        acc.y = wself * hi.y;
        for (int j = start; j < end; ++j) {
            int sv = col_src[j];
            float w = __expf(ebuf[j] - m) * inv_s;
            float2 hs = *(const float2*)&H[sv * 128 + lane * 2];
            acc.x += w * hs.x;
            acc.y += w * hs.y;
        }
    }

    float2 bv = *(const float2*)&bias[lane * 2];
    float2 o;
    o.x = acc.x + bv.x;
    o.y = acc.y + bv.y;
    *(float2*)&Zout[node * 128 + lane * 2] = o;
}

// ---------------- BatchNorm (training stats, weight=1 bias=0) + ReLU
__global__ void k_bnstats(const float* __restrict__ Z, float* __restrict__ part) {
    int c = threadIdx.x;   // 128
    float s = 0.f, sq = 0.f;
    for (int i = blockIdx.x; i < N_NODES; i += gridDim.x) {
        float v = Z[i * 128 + c];
        s += v;
        sq += v * v;
    }
    part[blockIdx.x * 256 + c] = s;
    part[blockIdx.x * 256 + 128 + c] = sq;
}

__global__ void k_bnfinal(const float* __restrict__ part, float* __restrict__ mu,
                          float* __restrict__ rs) {
    int c = threadIdx.x;   // 128
    float s = 0.f, sq = 0.f;
    for (int b = 0; b < 512; ++b) {
        s += part[b * 256 + c];
        sq += part[b * 256 + 128 + c];
    }
    float m = s / (float)N_NODES;
    float var = sq / (float)N_NODES - m * m;
    mu[c] = m;
    rs[c] = rsqrtf(var + EPS);
}

__global__ void k_bnapply(const float* __restrict__ Zin, const float* __restrict__ mu,
                          const float* __restrict__ rs, float* __restrict__ Zout) {
    int idx = blockIdx.x * blockDim.x + threadIdx.x;   // over N*32 float4
    if (idx >= N_NODES * 32) return;
    int c4 = idx & 31;
    float4 v = ((const float4*)Zin)[idx];
    float4 m4 = ((const float4*)mu)[c4];
    float4 r4 = ((const float4*)rs)[c4];
    v.x = fmaxf((v.x - m4.x) * r4.x, 0.f);
    v.y = fmaxf((v.y - m4.y) * r4.y, 0.f);
    v.z = fmaxf((v.z - m4.z) * r4.z, 0.f);
    v.w = fmaxf((v.w - m4.w) * r4.w, 0.f);
    ((float4*)Zout)[idx] = v;
}

extern "C" void kernel_launch(void* const* d_in, const int* in_sizes, int n_in,
                              void* d_out, int out_size, void* d_ws, size_t ws_size,
                              hipStream_t stream) {
    const float* x = (const float*)d_in[0];
    const int* ei = (const int*)d_in[1];
    const int* srcp = ei;
    const int* dstp = ei + N_EDGES;
    const float* W = (const float*)d_in[2];
    const float* a_src = (const float*)d_in[3];
    const float* a_dst = (const float*)d_in[4];
    const float* bias = (const float*)d_in[5];
    float* out = (float*)d_out;

    char* ws = (char*)d_ws;
    size_t off = 0;
    auto alloc = [&](size_t bytes) -> void* {
        void* p = ws + off;
        off = (off + bytes + 255) & ~(size_t)255;
        return p;
    };
    int* deg      = (int*)alloc(N_NODES * 4);
    int* fill     = (int*)alloc(N_NODES * 4);
    int* row_ptr  = (int*)alloc((N_NODES + 1) * 4);
    int* col_src  = (int*)alloc(N_EDGES * 4);
    float* ebuf   = (float*)alloc(N_EDGES * 4);
    float* hbuf   = (float*)alloc((size_t)N_NODES * DIM * 4);
    float* zbuf   = (float*)alloc((size_t)N_NODES * DIM * 4);
    float* asb    = (float*)alloc(N_NODES * 4);
    float* adb    = (float*)alloc(N_NODES * 4);
    float* part   = (float*)alloc(512 * 256 * 4);
    float* mu     = (float*)alloc(128 * 4);
    float* rsg    = (float*)alloc(128 * 4);
    if (off > ws_size) return;   // workspace too small: fail loudly

    hipMemsetAsync(deg, 0, N_NODES * 4, stream);
    hipMemsetAsync(fill, 0, N_NODES * 4, stream);
    k_degree<<<(N_EDGES + 255) / 256, 256, 0, stream>>>(dstp, deg);
    k_scan<<<1, 1024, 0, stream>>>(deg, row_ptr);
    k_scatter<<<(N_EDGES + 255) / 256, 256, 0, stream>>>(srcp, dstp, row_ptr, fill, col_src);

    const float* zin = x;
    for (int l = 0; l < 3; ++l) {
        k_gemm<<<(N_NODES + 31) / 32, 256, 0, stream>>>(zin, W + l * DIM * DIM, hbuf);
        k_alpha<<<(N_NODES + 3) / 4, 256, 0, stream>>>(hbuf, a_src + l * DIM, a_dst + l * DIM,
                                                       asb, adb);
        k_aggregate<<<(N_NODES + 3) / 4, 256, 0, stream>>>(row_ptr, col_src, hbuf, asb, adb,
                                                           bias + l * DIM, zbuf, ebuf);
        k_bnstats<<<512, 128, 0, stream>>>(zbuf, part);
        k_bnfinal<<<1, 128, 0, stream>>>(part, mu, rsg);
        float* zo = (l == 2) ? out : zbuf;
        k_bnapply<<<(N_NODES * 32 + 255) / 256, 256, 0, stream>>>(zbuf, mu, rsg, zo);
        zin = zbuf;
    }
}

// Round 2
// 739.574 us; speedup vs baseline: 1.4030x; 1.4030x over previous
//
#include <hip/hip_runtime.h>
#include <hip/hip_bf16.h>
#include <math.h>

#define N_NODES 50000
#define N_EDGES 1600000
#define DIM 128
#define EPS 1e-5f
#define SLOPE 0.2f
#define NB_SCAN 196   // ceil(50000/256)

__device__ __forceinline__ float lrelu(float x) { return x > 0.f ? x : SLOPE * x; }

__device__ __forceinline__ unsigned short f2bf(float f) {
    unsigned u = __float_as_uint(f);
    unsigned r = (u + 0x7fffu + ((u >> 16) & 1u)) >> 16;
    return (unsigned short)r;
}

// load 2 consecutive bf16 as float2
__device__ __forceinline__ float2 ldh2(const unsigned short* p) {
    unsigned u = *(const unsigned*)p;
    float2 r;
    r.x = __uint_as_float(u << 16);
    r.y = __uint_as_float(u & 0xffff0000u);
    return r;
}

// ---------------- CSR build ----------------
__global__ void k_degree(const int* __restrict__ dst, int* __restrict__ deg) {
    int e = blockIdx.x * blockDim.x + threadIdx.x;
    if (e < N_EDGES) atomicAdd(&deg[dst[e]], 1);
}

// block-level exclusive scan, 256 elems per block
__global__ void k_scan1(const int* __restrict__ deg, int* __restrict__ partial,
                        int* __restrict__ bsum) {
    __shared__ int s[256];
    int t = threadIdx.x, g = blockIdx.x * 256 + t;
    int v = (g < N_NODES) ? deg[g] : 0;
    s[t] = v;
    __syncthreads();
    for (int off = 1; off < 256; off <<= 1) {
        int x = s[t];
        int y = (t >= off) ? s[t - off] : 0;
        __syncthreads();
        s[t] = x + y;
        __syncthreads();
    }
    if (g < N_NODES) partial[g] = s[t] - v;
    if (t == 255) bsum[blockIdx.x] = s[255];
}

__global__ void k_scan2(const int* __restrict__ bsum, int* __restrict__ boff) {
    __shared__ int s[256];
    int t = threadIdx.x;
    int v = (t < NB_SCAN) ? bsum[t] : 0;
    s[t] = v;
    __syncthreads();
    for (int off = 1; off < 256; off <<= 1) {
        int x = s[t];
        int y = (t >= off) ? s[t - off] : 0;
        __syncthreads();
        s[t] = x + y;
        __syncthreads();
    }
    if (t < NB_SCAN) boff[t] = s[t] - v;
    if (t == 255) boff[NB_SCAN] = s[255];
}

__global__ void k_scan3(const int* __restrict__ partial, const int* __restrict__ boff,
                        int* __restrict__ row_ptr) {
    int g = blockIdx.x * 256 + threadIdx.x;
    if (g < N_NODES) row_ptr[g] = partial[g] + boff[blockIdx.x];
    if (g == 0) row_ptr[N_NODES] = boff[NB_SCAN];
}

__global__ void k_scatter(const int* __restrict__ src, const int* __restrict__ dst,
                          const int* __restrict__ row_ptr, int* __restrict__ fill,
                          int* __restrict__ col_src) {
    int e = blockIdx.x * blockDim.x + threadIdx.x;
    if (e < N_EDGES) {
        int d = dst[e];
        int pos = row_ptr[d] + atomicAdd(&fill[d], 1);
        col_src[pos] = src[e];
    }
}

// ---------------- GEMM: H = Z @ W  (fp32, 32 rows x 128 cols / block, 4x4 per thread)
// Writes fp32 H (for alpha logits) and bf16 Hb (for the feature gather).
__global__ void k_gemm(const float* __restrict__ Z, const float* __restrict__ W,
                       float* __restrict__ H, unsigned short* __restrict__ Hb) {
    __shared__ float zT[128][36];
    __shared__ float Ws[64][128];
    int tid = threadIdx.x;
    int row0 = blockIdx.x * 32;

    for (int i = tid; i < 32 * 128; i += 256) {
        int r = i >> 7;
        int k = i & 127;
        int gr = row0 + r;
        zT[k][r] = (gr < N_NODES) ? Z[gr * 128 + k] : 0.f;
    }

    float acc[4][4];
#pragma unroll
    for (int a = 0; a < 4; a++)
#pragma unroll
        for (int b = 0; b < 4; b++) acc[a][b] = 0.f;

    int cg = tid & 31;
    int rg = tid >> 5;

    for (int kc = 0; kc < 2; ++kc) {
        __syncthreads();
        for (int i = tid; i < 64 * 128 / 4; i += 256) {
            int k = i >> 5;
            int c4 = i & 31;
            *(float4*)&Ws[k][c4 * 4] = *(const float4*)&W[(kc * 64 + k) * 128 + c4 * 4];
        }
        __syncthreads();
#pragma unroll 8
        for (int kk = 0; kk < 64; ++kk) {
            int k = kc * 64 + kk;
            float4 wv = *(float4*)&Ws[kk][cg * 4];
            float4 zv = *(float4*)&zT[k][rg * 4];
            acc[0][0] += zv.x * wv.x; acc[0][1] += zv.x * wv.y; acc[0][2] += zv.x * wv.z; acc[0][3] += zv.x * wv.w;
            acc[1][0] += zv.y * wv.x; acc[1][1] += zv.y * wv.y; acc[1][2] += zv.y * wv.z; acc[1][3] += zv.y * wv.w;
            acc[2][0] += zv.z * wv.x; acc[2][1] += zv.z * wv.y; acc[2][2] += zv.z * wv.z; acc[2][3] += zv.z * wv.w;
            acc[3][0] += zv.w * wv.x; acc[3][1] += zv.w * wv.y; acc[3][2] += zv.w * wv.z; acc[3][3] += zv.w * wv.w;
        }
    }

#pragma unroll
    for (int a = 0; a < 4; a++) {
        int gr = row0 + rg * 4 + a;
        if (gr < N_NODES) {
            *(float4*)&H[gr * 128 + cg * 4] =
                make_float4(acc[a][0], acc[a][1], acc[a][2], acc[a][3]);
            ushort4 hb;
            hb.x = f2bf(acc[a][0]); hb.y = f2bf(acc[a][1]);
            hb.z = f2bf(acc[a][2]); hb.w = f2bf(acc[a][3]);
            *(ushort4*)&Hb[gr * 128 + cg * 4] = hb;
        }
    }
}

// ---------------- per-node attention coefficients
__global__ void k_alpha(const float* __restrict__ H, const float* __restrict__ a_src,
                        const float* __restrict__ a_dst, float* __restrict__ as_,
                        float* __restrict__ ad_) {
    int node = blockIdx.x * 4 + (threadIdx.x >> 6);
    int lane = threadIdx.x & 63;
    if (node >= N_NODES) return;
    float2 h = *(const float2*)&H[node * 128 + lane * 2];
    float2 s = *(const float2*)&a_src[lane * 2];
    float2 d = *(const float2*)&a_dst[lane * 2];
    float ps = h.x * s.x + h.y * s.y;
    float pd = h.x * d.x + h.y * d.y;
#pragma unroll
    for (int off = 32; off; off >>= 1) {
        ps += __shfl_xor(ps, off);
        pd += __shfl_xor(pd, off);
    }
    if (lane == 0) { as_[node] = ps; ad_[node] = pd; }
}

// ---------------- segment softmax + weighted aggregation (one wave per dst node)
__global__ void k_aggregate(const int* __restrict__ row_ptr, const int* __restrict__ col_src,
                            const unsigned short* __restrict__ Hb,
                            const float* __restrict__ as_, const float* __restrict__ ad_,
                            const float* __restrict__ bias, float* __restrict__ Zout,
                            float* __restrict__ ebuf) {
    int node = blockIdx.x * 4 + (threadIdx.x >> 6);
    int lane = threadIdx.x & 63;
    if (node >= N_NODES) return;

    int start = row_ptr[node], end = row_ptr[node + 1];
    int deg = end - start;
    float ad_i = ad_[node];
    float eself = lrelu(as_[node] + ad_i);
    float m = eself;
    float2 acc;
    float2 hi = ldh2(&Hb[(size_t)node * 128 + lane * 2]);

    if (deg <= 128) {
        int s0 = 0, s1 = 0;
        float e0 = -INFINITY, e1 = -INFINITY;
        if (start + lane < end) {
            s0 = col_src[start + lane];
            e0 = lrelu(as_[s0] + ad_i);
            m = fmaxf(m, e0);
        }
        if (start + 64 + lane < end) {
            s1 = col_src[start + 64 + lane];
            e1 = lrelu(as_[s1] + ad_i);
            m = fmaxf(m, e1);
        }
#pragma unroll
        for (int off = 32; off; off >>= 1) m = fmaxf(m, __shfl_xor(m, off));
        float w0 = __expf(e0 - m);   // 0 for invalid lanes
        float w1 = __expf(e1 - m);
        float p = w0 + w1;
#pragma unroll
        for (int off = 32; off; off >>= 1) p += __shfl_xor(p, off);
        float pself = __expf(eself - m);
        float inv_s = 1.f / (p + pself);
        w0 *= inv_s;
        w1 *= inv_s;
        float wself = pself * inv_s;
        acc.x = wself * hi.x;
        acc.y = wself * hi.y;

        int jmax = deg < 64 ? deg : 64;
        int j = 0;
        for (; j + 4 <= jmax; j += 4) {
            float wa = __shfl(w0, j),     wb = __shfl(w0, j + 1);
            float wc = __shfl(w0, j + 2), wd = __shfl(w0, j + 3);
            int   sa = __shfl(s0, j),     sb = __shfl(s0, j + 1);
            int   sc = __shfl(s0, j + 2), sd = __shfl(s0, j + 3);
            float2 ha = ldh2(&Hb[(size_t)sa * 128 + lane * 2]);
            float2 hbv = ldh2(&Hb[(size_t)sb * 128 + lane * 2]);
            float2 hc = ldh2(&Hb[(size_t)sc * 128 + lane * 2]);
            float2 hd = ldh2(&Hb[(size_t)sd * 128 + lane * 2]);
            acc.x += wa * ha.x + wb * hbv.x + wc * hc.x + wd * hd.x;
            acc.y += wa * ha.y + wb * hbv.y + wc * hc.y + wd * hd.y;
        }
        for (; j < jmax; ++j) {
            float w = __shfl(w0, j);
            int sv = __shfl(s0, j);
            float2 hs = ldh2(&Hb[(size_t)sv * 128 + lane * 2]);
            acc.x += w * hs.x;
            acc.y += w * hs.y;
        }
        for (j = 64; j < deg; ++j) {
            float w = __shfl(w1, j - 64);
            int sv = __shfl(s1, j - 64);
            float2 hs = ldh2(&Hb[(size_t)sv * 128 + lane * 2]);
            acc.x += w * hs.x;
            acc.y += w * hs.y;
        }
    } else {
        for (int j = start + lane; j < end; j += 64) {
            int sj = col_src[j];
            float e = lrelu(as_[sj] + ad_i);
            ebuf[j] = e;
            m = fmaxf(m, e);
        }
#pragma unroll
        for (int off = 32; off; off >>= 1) m = fmaxf(m, __shfl_xor(m, off));
        float p = 0.f;
        for (int j = start + lane; j < end; j += 64) p += __expf(ebuf[j] - m);
#pragma unroll
        for (int off = 32; off; off >>= 1) p += __shfl_xor(p, off);
        float pself = __expf(eself - m);
        float inv_s = 1.f / (p + pself);
        float wself = pself * inv_s;
        acc.x = wself * hi.x;
        acc.y = wself * hi.y;
        for (int j = start; j < end; ++j) {
            int sv = col_src[j];
            float w = __expf(ebuf[j] - m) * inv_s;
            float2 hs = ldh2(&Hb[(size_t)sv * 128 + lane * 2]);
            acc.x += w * hs.x;
            acc.y += w * hs.y;
        }
    }

    float2 bv = *(const float2*)&bias[lane * 2];
    float2 o;
    o.x = acc.x + bv.x;
    o.y = acc.y + bv.y;
    *(float2*)&Zout[(size_t)node * 128 + lane * 2] = o;
}

// ---------------- BatchNorm (training stats) + ReLU
__global__ void k_bnstats(const float* __restrict__ Z, float* __restrict__ part) {
    int c = threadIdx.x;
    float s = 0.f, sq = 0.f;
    for (int i = blockIdx.x; i < N_NODES; i += gridDim.x) {
        float v = Z[(size_t)i * 128 + c];
        s += v;
        sq += v * v;
    }
    part[blockIdx.x * 256 + c] = s;
    part[blockIdx.x * 256 + 128 + c] = sq;
}

__global__ void k_bnfinal(const float* __restrict__ part, float* __restrict__ mu,
                          float* __restrict__ rs) {
    int c = threadIdx.x;
    float s = 0.f, sq = 0.f;
    for (int b = 0; b < 512; ++b) {
        s += part[b * 256 + c];
        sq += part[b * 256 + 128 + c];
    }
    float m = s / (float)N_NODES;
    float var = sq / (float)N_NODES - m * m;
    mu[c] = m;
    rs[c] = rsqrtf(var + EPS);
}

__global__ void k_bnapply(const float* __restrict__ Zin, const float* __restrict__ mu,
                          const float* __restrict__ rs, float* __restrict__ Zout) {
    int idx = blockIdx.x * blockDim.x + threadIdx.x;
    if (idx >= N_NODES * 32) return;
    int c4 = idx & 31;
    float4 v = ((const float4*)Zin)[idx];
    float4 m4 = ((const float4*)mu)[c4];
    float4 r4 = ((const float4*)rs)[c4];
    v.x = fmaxf((v.x - m4.x) * r4.x, 0.f);
    v.y = fmaxf((v.y - m4.y) * r4.y, 0.f);
    v.z = fmaxf((v.z - m4.z) * r4.z, 0.f);
    v.w = fmaxf((v.w - m4.w) * r4.w, 0.f);
    ((float4*)Zout)[idx] = v;
}

extern "C" void kernel_launch(void* const* d_in, const int* in_sizes, int n_in,
                              void* d_out, int out_size, void* d_ws, size_t ws_size,
                              hipStream_t stream) {
    const float* x = (const float*)d_in[0];
    const int* ei = (const int*)d_in[1];
    const int* srcp = ei;
    const int* dstp = ei + N_EDGES;
    const float* W = (const float*)d_in[2];
    const float* a_src = (const float*)d_in[3];
    const float* a_dst = (const float*)d_in[4];
    const float* bias = (const float*)d_in[5];
    float* out = (float*)d_out;

    char* ws = (char*)d_ws;
    size_t off = 0;
    auto alloc = [&](size_t bytes) -> void* {
        void* p = ws + off;
        off = (off + bytes + 255) & ~(size_t)255;
        return p;
    };
    int* deg      = (int*)alloc(N_NODES * 4);
    int* fill     = (int*)alloc(N_NODES * 4);
    int* row_ptr  = (int*)alloc((N_NODES + 1) * 4);
    int* col_src  = (int*)alloc(N_EDGES * 4);
    float* ebuf   = (float*)alloc(N_EDGES * 4);       // also aliased for scan temps
    float* hbuf   = (float*)alloc((size_t)N_NODES * DIM * 4);
    unsigned short* hbf = (unsigned short*)alloc((size_t)N_NODES * DIM * 2);
    float* zbuf   = (float*)alloc((size_t)N_NODES * DIM * 4);
    float* asb    = (float*)alloc(N_NODES * 4);
    float* adb    = (float*)alloc(N_NODES * 4);
    float* part   = (float*)alloc(512 * 256 * 4);
    float* mu     = (float*)alloc(128 * 4);
    float* rsg    = (float*)alloc(128 * 4);
    if (off > ws_size) return;

    // scan temporaries alias ebuf (disjoint phases)
    int* partial = (int*)ebuf;
    int* bsum    = partial + N_NODES;
    int* boff    = bsum + 256;

    hipMemsetAsync(deg, 0, N_NODES * 4, stream);
    hipMemsetAsync(fill, 0, N_NODES * 4, stream);
    k_degree<<<(N_EDGES + 255) / 256, 256, 0, stream>>>(dstp, deg);
    k_scan1<<<NB_SCAN, 256, 0, stream>>>(deg, partial, bsum);
    k_scan2<<<1, 256, 0, stream>>>(bsum, boff);
    k_scan3<<<NB_SCAN, 256, 0, stream>>>(partial, boff, row_ptr);
    k_scatter<<<(N_EDGES + 255) / 256, 256, 0, stream>>>(srcp, dstp, row_ptr, fill, col_src);

    const float* zin = x;
    for (int l = 0; l < 3; ++l) {
        k_gemm<<<(N_NODES + 31) / 32, 256, 0, stream>>>(zin, W + l * DIM * DIM, hbuf, hbf);
        k_alpha<<<(N_NODES + 3) / 4, 256, 0, stream>>>(hbuf, a_src + l * DIM, a_dst + l * DIM,
                                                       asb, adb);
        k_aggregate<<<(N_NODES + 3) / 4, 256, 0, stream>>>(row_ptr, col_src, hbf, asb, adb,
                                                           bias + l * DIM, zbuf, ebuf);
        k_bnstats<<<512, 128, 0, stream>>>(zbuf, part);
        k_bnfinal<<<1, 128, 0, stream>>>(part, mu, rsg);
        float* zo = (l == 2) ? out : zbuf;
        k_bnapply<<<(N_NODES * 32 + 255) / 256, 256, 0, stream>>>(zbuf, mu, rsg, zo);
        zin = zbuf;
    }
}